// Round 8
// baseline (270.584 us; speedup 1.0000x reference)
//
#include <hip/hip_runtime.h>
#include <hip/hip_bf16.h>

#define NH      12
#define HD      64
#define HID     768
#define B_      2
#define D_      16
#define QL      32
#define SL      512
#define SEQ     545
#define RPB     8225
#define TOT_ROWS 16450
#define PAD_ROWS 16512       // 129*128
#define VT_R    8256         // Vt rows/batch: cls=0, query 1..32, doc d at 40+d*512
#define WSZ     589824       // 768*768
#define SCALE_  0.125f
#define LOG2E   1.4426950408889634f
#define QSF     0.18033688011112042f   // SCALE_*LOG2E, folded into Wq/bq

typedef __attribute__((ext_vector_type(8))) short short8;
typedef __attribute__((ext_vector_type(4))) short short4v;
typedef __attribute__((ext_vector_type(4))) float float4v;
typedef __attribute__((ext_vector_type(2))) unsigned int uint2v;

__device__ __forceinline__ short f2bf(float f) {
    __hip_bfloat16 h = __float2bfloat16(f);
    short s; __builtin_memcpy(&s, &h, 2);
    return s;
}

// v_cvt_pk_bf16_f32: lo16=bf16(a), hi16=bf16(b) — no builtin on gfx950
__device__ __forceinline__ unsigned int cvtpk(float a, float b) {
    unsigned int r;
    asm("v_cvt_pk_bf16_f32 %0, %1, %2" : "=v"(r) : "v"(a), "v"(b));
    return r;
}

// async global->LDS 16B/lane; lds base wave-uniform (HW adds lane*16)
__device__ __forceinline__ void gl2lds16(const short* g, short* l) {
    __builtin_amdgcn_global_load_lds(
        (const __attribute__((address_space(1))) void*)g,
        (__attribute__((address_space(3))) void*)l, 16, 0, 0);
}

#define PACK_BLKS  12384     // PAD_ROWS*HID/4/256
#define WPACK_BLKS 1728      // 3*WSZ/4/256

// ---------------------------------------------------------------------------
// Kernel 1 (fused): gather cls/query/doc fp32 -> bf16 X [PAD_ROWS x 768],
// and W fp32 -> bf16 (Wq pre-scaled by SCALE*log2e; Wb parked in d_out).
// ---------------------------------------------------------------------------
__global__ __launch_bounds__(256) void pack_all(
    const float* __restrict__ cls, const float* __restrict__ query,
    const float* __restrict__ doc,
    const float* __restrict__ Wq, const float* __restrict__ Wk,
    const float* __restrict__ Wv,
    short* __restrict__ X, short* __restrict__ Wb)
{
    int bid = blockIdx.x;
    if (bid < PACK_BLKS) {
        int idx = (bid * 256 + threadIdx.x) * 4;
        int row = idx / HID;
        int col = idx - row * HID;
        float4 v = make_float4(0.f, 0.f, 0.f, 0.f);
        if (row < TOT_ROWS) {
            int b = row / RPB;
            int r = row - b * RPB;
            const float* src;
            if (r == 0)        src = cls   + b * HID + col;
            else if (r < 33)   src = query + ((size_t)(b * QL + (r - 1))) * HID + col;
            else               src = doc   + ((size_t)(b * (D_ * SL) + (r - 33))) * HID + col;
            v = *reinterpret_cast<const float4*>(src);
        }
        short4v o;
        o[0] = f2bf(v.x); o[1] = f2bf(v.y); o[2] = f2bf(v.z); o[3] = f2bf(v.w);
        *reinterpret_cast<short4v*>(X + idx) = o;
    } else {
        int idx = ((bid - PACK_BLKS) * 256 + threadIdx.x) * 4;
        int z = idx / WSZ;
        int r = idx - z * WSZ;
        const float* src = (z == 0 ? Wq : (z == 1 ? Wk : Wv)) + r;
        float sc = (z == 0) ? QSF : 1.0f;   // fold qk-scale*log2e into Wq
        float4 v = *reinterpret_cast<const float4*>(src);
        short4v o;
        o[0] = f2bf(v.x * sc); o[1] = f2bf(v.y * sc);
        o[2] = f2bf(v.z * sc); o[3] = f2bf(v.w * sc);
        *reinterpret_cast<short4v*>(Wb + idx) = o;
    }
}

// ---------------------------------------------------------------------------
// Kernel 2: projection GEMM, 128x128 tile, BK=64 (12 K-steps), single-barrier
// double-buffered K-loop. Q/K/V in ONE dispatch. XOR chunk-swizzled LDS.
// Grid locality: fast dim = (n,z); XCD-chunked bijective remap (m204).
// zi==0 (Q): output pre-scaled by QSF (W and bias scaled).
// zi==2 (V): A=W-frag, B=X-frag so D[m=wcol][n=xrow]; Vt stores become
// 16-lane contiguous 32B runs along Vt's fast (token) dim.
// ---------------------------------------------------------------------------
__global__ __launch_bounds__(256) void proj4u(
    const short* __restrict__ X, const short* __restrict__ Wb,
    const float* __restrict__ bq, const float* __restrict__ bk,
    const float* __restrict__ bv,
    short* __restrict__ Qb, short* __restrict__ Kb, short* __restrict__ Vt)
{
    __shared__ short Xs[2][128 * 64];
    __shared__ short Ws[2][128 * 64];

    int tid = threadIdx.x, lane = tid & 63, wave = tid >> 6;

    // ---- XCD-aware bijective remap: nwg = 18*129 = 2322 = 8*290 + 2 ----
    int lin = blockIdx.x + 18 * blockIdx.y;
    {
        const int q = 290, r = 2;
        int xcd = lin & 7, seq = lin >> 3;
        lin = (xcd < r ? xcd * (q + 1) : r * (q + 1) + (xcd - r) * q) + seq;
    }
    int mblk = lin / 18;
    int nz   = lin - mblk * 18;
    int zi   = nz % 3;          // z fastest
    int nblk = nz / 3;
    bool vsw = (zi == 2);
    const short* W = Wb + (size_t)zi * WSZ;
    int m0 = mblk * 128, n0 = nblk * 128;

    int moff = (wave & 1) * 64, noff = (wave >> 1) * 64;
    int lr = lane & 15, lg = lane >> 4;

    // staging sources: slot s = p*256+tid -> row = s>>3, chunk c = s&7;
    // position c in LDS holds logical chunk (c ^ (row&7)) of the 64-K window.
    const short* xsrc[4];
    const short* wsrc[4];
#pragma unroll
    for (int p = 0; p < 4; ++p) {
        int s = p * 256 + tid;
        int row = s >> 3, c = s & 7;
        int col = (c ^ (row & 7)) * 8;
        xsrc[p] = X + (size_t)(m0 + row) * HID + col;
        wsrc[p] = W + (size_t)(n0 + row) * HID + col;
    }

    float4v acc[4][4];
    for (int mi = 0; mi < 4; ++mi)
        for (int ni = 0; ni < 4; ++ni)
            acc[mi][ni] = (float4v){0.f, 0.f, 0.f, 0.f};

#define PSTAGE(bufi, kt) do {                                               \
    _Pragma("unroll")                                                       \
    for (int p = 0; p < 4; ++p) {                                           \
        gl2lds16(xsrc[p] + (kt) * 64,                                       \
                 &Xs[bufi][(p * 256 + (tid & 0xC0)) * 8]);                  \
        gl2lds16(wsrc[p] + (kt) * 64,                                       \
                 &Ws[bufi][(p * 256 + (tid & 0xC0)) * 8]);                  \
    } } while (0)

    PSTAGE(0, 0);
#pragma unroll
    for (int kt = 0; kt < 12; ++kt) {
        __syncthreads();                     // drains stage(kt); prev compute done
        if (kt < 11) PSTAGE((kt + 1) & 1, kt + 1);
        const short* xb = Xs[kt & 1];
        const short* wb = Ws[kt & 1];
        short8 afl[4], afh[4], bfl[4], bfh[4];
        for (int mi = 0; mi < 4; ++mi) {
            int r = moff + mi * 16 + lr;
            int x0 = lg ^ (r & 7);
            afl[mi] = *reinterpret_cast<const short8*>(&xb[r * 64 + x0 * 8]);
            afh[mi] = *reinterpret_cast<const short8*>(&xb[r * 64 + (x0 ^ 4) * 8]);
        }
        for (int ni = 0; ni < 4; ++ni) {
            int r = noff + ni * 16 + lr;
            int x0 = lg ^ (r & 7);
            bfl[ni] = *reinterpret_cast<const short8*>(&wb[r * 64 + x0 * 8]);
            bfh[ni] = *reinterpret_cast<const short8*>(&wb[r * 64 + (x0 ^ 4) * 8]);
        }
        if (!vsw) {
            for (int mi = 0; mi < 4; ++mi)
                for (int ni = 0; ni < 4; ++ni) {
                    acc[mi][ni] = __builtin_amdgcn_mfma_f32_16x16x32_bf16(
                        afl[mi], bfl[ni], acc[mi][ni], 0, 0, 0);
                    acc[mi][ni] = __builtin_amdgcn_mfma_f32_16x16x32_bf16(
                        afh[mi], bfh[ni], acc[mi][ni], 0, 0, 0);
                }
        } else {
            for (int mi = 0; mi < 4; ++mi)
                for (int ni = 0; ni < 4; ++ni) {
                    acc[mi][ni] = __builtin_amdgcn_mfma_f32_16x16x32_bf16(
                        bfl[ni], afl[mi], acc[mi][ni], 0, 0, 0);
                    acc[mi][ni] = __builtin_amdgcn_mfma_f32_16x16x32_bf16(
                        bfh[ni], afh[mi], acc[mi][ni], 0, 0, 0);
                }
        }
    }
#undef PSTAGE

    if (!vsw) {
        short* Y = zi == 0 ? Qb : Kb;
        const float* bias = zi == 0 ? bq : bk;
        float bsc = zi == 0 ? QSF : 1.0f;
        for (int ni = 0; ni < 4; ++ni) {
            int gcol = n0 + noff + ni * 16 + lr;
            float bb = bias[gcol] * bsc;
            for (int mi = 0; mi < 4; ++mi) {
                int growb = m0 + moff + mi * 16 + lg * 4;
                for (int r = 0; r < 4; ++r)
                    Y[(size_t)(growb + r) * HID + gcol] = f2bf(acc[mi][ni][r] + bb);
            }
        }
    } else {
        // D[m=wcol = noff+ni*16+lg*4+r][n=xrow = moff+mi*16+lr]
        for (int ni = 0; ni < 4; ++ni) {
            float4 b4 = *reinterpret_cast<const float4*>(&bv[n0 + noff + ni * 16 + lg * 4]);
            const float* bbr = reinterpret_cast<const float*>(&b4);
            for (int mi = 0; mi < 4; ++mi) {
                int grow = m0 + moff + mi * 16 + lr;
                if (grow >= TOT_ROWS) continue;
                int b  = grow >= RPB ? 1 : 0;
                int rb = grow - b * RPB;
                int vr = rb < 33 ? rb : rb + 7;        // doc rows at 40+
                size_t cb = ((size_t)(b * HID + n0 + noff + ni * 16 + lg * 4)) * VT_R;
                for (int r = 0; r < 4; ++r)
                    Vt[cb + (size_t)r * VT_R + vr] = f2bf(acc[mi][ni][r] + bbr[r]);
            }
        }
    }
}

// ---------------------------------------------------------------------------
// Kernel 3: flash attention (S^T form), 128 q/block, 512 threads / 8 waves,
// 2-buffer ring, LDS 35KB -> 4 blocks/CU (32 waves = full slot budget).
// Round-6 lesson: 12-wave blocks achieved only ~1 resident block (29% occ);
// finer blocks give the scheduler granularity, and with 4 independent
// blocks/CU the per-tile drain stall is hidden by other blocks' waves
// (m114 overlap, as in proj4u).
// 2-buffer discipline: stage(kt+1) issued at TOP of tile kt, drained by
// the __syncthreads() at its END (~1 compute-tile of flight covers L2
// latency); buf[(kt+1)&1]'s prior readers finished at the end of tile kt-1.
// ROUND-7 FIX: mask init is a strided loop — 512 threads must cover 576
// entries (the `if (tid<576)` left 512..575 uninitialized -> garbage mask).
// Softmax: Q pre-scaled; mask preloaded into QK^T acc; defer-max via
// per-lane max + __any; per-lane partial sums reduced in epilogue;
// in-register P->A-frag repack (cvt_pk + permlane).
// Token order: doc 0..511, cls 512, query 513..544, pad 545.. (-inf mask).
// ---------------------------------------------------------------------------
__global__ __launch_bounds__(512) void attn7(
    const short* __restrict__ Qb, const short* __restrict__ Kb,
    const short* __restrict__ Vt,
    const float* __restrict__ qmask, const float* __restrict__ dmask,
    float* __restrict__ out)
{
    __shared__ short Ks[2][64 * 64];
    __shared__ short Vs[2][64 * 64];
    __shared__ float maskv[576];

    int tid  = threadIdx.x;
    int lane = tid & 63, wave = tid >> 6;

    // ---- XCD-aware remap: nwg = 5*384 = 1920 = 8*240 ----
    int lin = blockIdx.x + 5 * blockIdx.y;
    {
        int xcd = lin & 7, seq = lin >> 3;
        lin = xcd * 240 + seq;
    }
    int hbd = lin / 5;
    int qc  = lin - hbd * 5;
    int h = hbd >> 5, bd = hbd & 31;
    int b = bd >> 4, d = bd & 15;

    int lr = lane & 15, lg = lane >> 4, lk = lg * 8;
    int base = b * RPB;
    const short* vbase = Vt + (size_t)(b * HID + h * HD) * VT_R;

    // ---- hoisted staging addresses: 512 threads cover the full 64x128B
    // tile (1 K slot + 1 V slot each); LDS base wave-uniform ----
    int loffK = (tid & 0x1C0) * 8;
    const short *kp, *vp, *kp8, *vp8;
    {
        int r = tid >> 3, c = tid & 7;
        int colsw = (c ^ (r & 7)) * 8;
        // tiles 0..7: token = kt*64 + r, all doc rows (linear in kt)
        kp  = Kb + (size_t)(base + 33 + d * SL + r) * HID + h * HD + colsw;
        vp  = vbase + (size_t)r * VT_R + 40 + d * SL + colsw;
        // tile 8: token 512+r -> row base+min(r,32); V: vr = chunk
        int r8 = r > 32 ? 32 : r;
        kp8 = Kb + (size_t)(base + r8) * HID + h * HD + colsw;
        vp8 = vbase + (size_t)r * VT_R + colsw;
    }

#define ALIN(bufi, kt) do {                                       \
    gl2lds16(kp + (size_t)(kt) * 64 * HID, &Ks[bufi][loffK]);     \
    gl2lds16(vp + (kt) * 64, &Vs[bufi][loffK]); } while (0)
#define A8(bufi) do {                                             \
    gl2lds16(kp8, &Ks[bufi][loffK]);                              \
    gl2lds16(vp8, &Vs[bufi][loffK]); } while (0)

    ALIN(0, 0);

    for (int i = tid; i < 576; i += 512) {   // FIX: strided (512 thr, 576 ent)
        float mv;
        if (i < 512)       mv = dmask[(size_t)(b * D_ + d) * SL + i];
        else if (i == 512) mv = 0.f;
        else if (i < 545)  mv = qmask[b * QL + (i - 513)];
        else               mv = -INFINITY;
        maskv[i] = mv * LOG2E;
    }

    short8 bq0, bq1;
    {
        int qtok = qc * 128 + wave * 16 + lr;
        int qrow = qtok < 512 ? base + 33 + d * SL + qtok : base + qtok - 512;
        const short* qp = Qb + (size_t)qrow * HID + h * HD + lk;
        bq0 = *reinterpret_cast<const short8*>(qp);
        bq1 = *reinterpret_cast<const short8*>(qp + 32);
    }

    float m_i = -1e30f;
    float lp  = 0.f;                    // per-LANE partial row sum
    float4v o[4];
    for (int nt = 0; nt < 4; ++nt) o[nt] = (float4v){0.f, 0.f, 0.f, 0.f};

    __syncthreads();    // stage(0) landed, maskv visible

#pragma unroll
    for (int kt = 0; kt < 9; ++kt) {
        // stage(kt+1) first: max flight time before its drain at tile end
        if (kt < 7)       ALIN((kt + 1) & 1, kt + 1);
        else if (kt == 7) A8((kt + 1) & 1);

        const short* kb   = Ks[kt & 1];
        const short* vbuf = Vs[kt & 1];

        // ---- QK^T: lane holds P[key = kt*64+nt*16+lg*4+r][q = lr];
        //      mask pre-loaded into the accumulator, Q pre-scaled ----
        float p4[4][4];
        short8 kf0[4], kf1[4];
#pragma unroll
        for (int nt = 0; nt < 4; ++nt) {
            int r = nt * 16 + lr;
            int x0 = lg ^ (r & 7);
            kf0[nt] = *reinterpret_cast<const short8*>(&kb[r * 64 + x0 * 8]);
            kf1[nt] = *reinterpret_cast<const short8*>(&kb[r * 64 + (x0 ^ 4) * 8]);
        }
        __builtin_amdgcn_s_setprio(1);
#pragma unroll
        for (int nt = 0; nt < 4; ++nt) {
            float4v z = *reinterpret_cast<const float4v*>(
                &maskv[kt * 64 + nt * 16 + lg * 4]);
            z = __builtin_amdgcn_mfma_f32_16x16x32_bf16(kf0[nt], bq0, z, 0, 0, 0);
            z = __builtin_amdgcn_mfma_f32_16x16x32_bf16(kf1[nt], bq1, z, 0, 0, 0);
            for (int r = 0; r < 4; ++r) p4[nt][r] = z[r];
        }
        __builtin_amdgcn_s_setprio(0);

        // ---- per-LANE max (max3-fusable); no cross-lane in common path ----
        float c0 = fmaxf(fmaxf(p4[0][0], p4[0][1]), p4[0][2]);
        float c1 = fmaxf(fmaxf(p4[0][3], p4[1][0]), p4[1][1]);
        float c2 = fmaxf(fmaxf(p4[1][2], p4[1][3]), p4[2][0]);
        float c3 = fmaxf(fmaxf(p4[2][1], p4[2][2]), p4[2][3]);
        float c4 = fmaxf(fmaxf(p4[3][0], p4[3][1]), p4[3][2]);
        float lmax = fmaxf(fmaxf(fmaxf(c0, c1), fmaxf(c2, c3)),
                           fmaxf(c4, p4[3][3]));

        // ---- defer-max: rescale only if some row grows past m+8 ----
        if (__any(lmax > m_i + 8.0f)) {
            float tmx = fmaxf(lmax, __shfl_xor(lmax, 16));
            tmx = fmaxf(tmx, __shfl_xor(tmx, 32));       // row max (q=lr)
            float mnew = fmaxf(m_i, tmx);
            float alpha = exp2f(m_i - mnew);
            m_i = mnew;
            lp *= alpha;
            float al[4];
            for (int r = 0; r < 4; ++r) al[r] = __shfl(alpha, lg * 4 + r);
            for (int nt = 0; nt < 4; ++nt)
                for (int r = 0; r < 4; ++r) o[nt][r] *= al[r];
        }

        // ---- exp2 + per-lane partial sum (P bounded by 2^8) ----
        for (int nt = 0; nt < 4; ++nt)
            for (int r = 0; r < 4; ++r)
                p4[nt][r] = exp2f(p4[nt][r] - m_i);
        float s0 = (p4[0][0] + p4[0][1]) + (p4[0][2] + p4[0][3]);
        float s1 = (p4[1][0] + p4[1][1]) + (p4[1][2] + p4[1][3]);
        float s2 = (p4[2][0] + p4[2][1]) + (p4[2][2] + p4[2][3]);
        float s3 = (p4[3][0] + p4[3][1]) + (p4[3][2] + p4[3][3]);
        lp += (s0 + s1) + (s2 + s3);

        // ---- in-register P -> PV A-fragment repack ----
        unsigned int wa[4], wbv[4];
        for (int nt = 0; nt < 4; ++nt) {
            wa[nt]  = cvtpk(p4[nt][0], p4[nt][1]);
            wbv[nt] = cvtpk(p4[nt][2], p4[nt][3]);
        }
        uint2v tA01 = __builtin_amdgcn_permlane32_swap(wa[0],  wa[1],  false, false);
        uint2v uA01 = __builtin_amdgcn_permlane16_swap(tA01[0], tA01[1], false, false);
        uint2v tB01 = __builtin_amdgcn_permlane32_swap(wbv[0], wbv[1], false, false);
        uint2v uB01 = __builtin_amdgcn_permlane16_swap(tB01[0], tB01[1], false, false);
        uint2v tA23 = __builtin_amdgcn_permlane32_swap(wa[2],  wa[3],  false, false);
        uint2v uA23 = __builtin_amdgcn_permlane16_swap(tA23[0], tA23[1], false, false);
        uint2v tB23 = __builtin_amdgcn_permlane32_swap(wbv[2], wbv[3], false, false);
        uint2v uB23 = __builtin_amdgcn_permlane16_swap(tB23[0], tB23[1], false, false);

        union { unsigned int u[4]; short8 s8; } A0, A1;
        A0.u[0] = uA01[0]; A0.u[1] = uB01[0]; A0.u[2] = uA01[1]; A0.u[3] = uB01[1];
        A1.u[0] = uA23[0]; A1.u[1] = uB23[0]; A1.u[2] = uA23[1]; A1.u[3] = uB23[1];
        short8 ap0 = A0.s8;
        short8 ap1 = A1.s8;

        // ---- PV ----
        __builtin_amdgcn_s_setprio(1);
#pragma unroll
        for (int nt = 0; nt < 4; ++nt) {
            int rd = nt * 16 + lr;
            int x0 = lg ^ (rd & 7);
            short8 bv0 = *reinterpret_cast<const short8*>(&vbuf[rd * 64 + x0 * 8]);
            short8 bv1 = *reinterpret_cast<const short8*>(&vbuf[rd * 64 + (x0 ^ 4) * 8]);
            o[nt] = __builtin_amdgcn_mfma_f32_16x16x32_bf16(ap0, bv0, o[nt], 0, 0, 0);
            o[nt] = __builtin_amdgcn_mfma_f32_16x16x32_bf16(ap1, bv1, o[nt], 0, 0, 0);
        }
        __builtin_amdgcn_s_setprio(0);

        if (kt < 8) __syncthreads();   // drains stage(kt+1); buf[kt&1] reads done
    }
#undef ALIN
#undef A8

    {
        float lt = lp;
        lt += __shfl_xor(lt, 16);
        lt += __shfl_xor(lt, 32);           // row total (q=lr), replicated
        float li[4];
        for (int r = 0; r < 4; ++r) li[r] = __shfl(lt, lg * 4 + r);
        for (int r = 0; r < 4; ++r) {
            int t = qc * 128 + wave * 16 + lg * 4 + r;
            if (t >= SEQ) continue;
            int seq = t < 512 ? 33 + t : (t == 512 ? 0 : t - 512);
            float inv = 1.f / li[r];
            float* op = out + ((size_t)(bd * SEQ + seq)) * HID + h * HD + lr;
            for (int nt = 0; nt < 4; ++nt)
                op[nt * 16] = o[nt][r] * inv;
        }
    }
}

// ---------------------------------------------------------------------------
extern "C" void kernel_launch(void* const* d_in, const int* in_sizes, int n_in,
                              void* d_out, int out_size, void* d_ws, size_t ws_size,
                              hipStream_t stream)
{
    const float* cls   = (const float*)d_in[0];
    const float* query = (const float*)d_in[1];
    const float* doc   = (const float*)d_in[2];
    const float* qmask = (const float*)d_in[3];
    const float* dmask = (const float*)d_in[4];
    const float* Wq = (const float*)d_in[5];
    const float* bq = (const float*)d_in[6];
    const float* Wk = (const float*)d_in[7];
    const float* bk = (const float*)d_in[8];
    const float* Wv = (const float*)d_in[9];
    const float* bv = (const float*)d_in[10];
    float* out = (float*)d_out;

    short* X  = (short*)d_ws;
    size_t seg = (size_t)PAD_ROWS * HID;
    short* Qb = X + seg;
    short* Kb = Qb + seg;
    short* Vt = Kb + seg;                 // 2*768*8256 == seg
    short* Wb = (short*)d_out;            // scratch; attn7 overwrites all of out

    pack_all<<<dim3(PACK_BLKS + WPACK_BLKS), 256, 0, stream>>>(
        cls, query, doc, Wq, Wk, Wv, X, Wb);
    proj4u<<<dim3(18, 129, 1), 256, 0, stream>>>(X, Wb, bq, bk, bv, Qb, Kb, Vt);
    attn7<<<dim3(5, NH * 32, 1), 512, 0, stream>>>(Qb, Kb, Vt, qmask, dmask, out);
}

// Round 9
// 258.664 us; speedup vs baseline: 1.0461x; 1.0461x over previous
//
#include <hip/hip_runtime.h>
#include <hip/hip_bf16.h>

#define NH      12
#define HD      64
#define HID     768
#define B_      2
#define D_      16
#define QL      32
#define SL      512
#define SEQ     545
#define RPB     8225
#define TOT_ROWS 16450
#define PAD_ROWS 16512       // 129*128
#define VT_R    8256         // Vt rows/batch: cls=0, query 1..32, doc d at 40+d*512
#define WSZ     589824       // 768*768
#define SCALE_  0.125f
#define LOG2E   1.4426950408889634f
#define QSF     0.18033688011112042f   // SCALE_*LOG2E, folded into Wq/bq

typedef __attribute__((ext_vector_type(8))) short short8;
typedef __attribute__((ext_vector_type(4))) short short4v;
typedef __attribute__((ext_vector_type(4))) float float4v;
typedef __attribute__((ext_vector_type(2))) unsigned int uint2v;

__device__ __forceinline__ short f2bf(float f) {
    __hip_bfloat16 h = __float2bfloat16(f);
    short s; __builtin_memcpy(&s, &h, 2);
    return s;
}

// v_cvt_pk_bf16_f32: lo16=bf16(a), hi16=bf16(b) — no builtin on gfx950
__device__ __forceinline__ unsigned int cvtpk(float a, float b) {
    unsigned int r;
    asm("v_cvt_pk_bf16_f32 %0, %1, %2" : "=v"(r) : "v"(a), "v"(b));
    return r;
}

// async global->LDS 16B/lane; lds base wave-uniform (HW adds lane*16)
__device__ __forceinline__ void gl2lds16(const short* g, short* l) {
    __builtin_amdgcn_global_load_lds(
        (const __attribute__((address_space(1))) void*)g,
        (__attribute__((address_space(3))) void*)l, 16, 0, 0);
}

#define PACK_BLKS  3096      // PAD_ROWS*HID/16/256
#define WPACK_BLKS 432       // 3*WSZ/16/256

// ---------------------------------------------------------------------------
// Kernel 1 (fused): gather cls/query/doc fp32 -> bf16 X [PAD_ROWS x 768],
// and W fp32 -> bf16 (Wq pre-scaled by SCALE*log2e; Wb parked in d_out).
// 16 elems/thread (4x fewer blocks/instructions than the old 4/thread).
// ---------------------------------------------------------------------------
__global__ __launch_bounds__(256) void pack_all(
    const float* __restrict__ cls, const float* __restrict__ query,
    const float* __restrict__ doc,
    const float* __restrict__ Wq, const float* __restrict__ Wk,
    const float* __restrict__ Wv,
    short* __restrict__ X, short* __restrict__ Wb)
{
    int bid = blockIdx.x;
    if (bid < PACK_BLKS) {
        int idx = (bid * 256 + threadIdx.x) * 16;
        int row = idx / HID;
        int col = idx - row * HID;        // 16 | 768 => all 16 in one row
        short o[16];
        if (row < TOT_ROWS) {
            int b = row / RPB;
            int r = row - b * RPB;
            const float* src;
            if (r == 0)        src = cls   + b * HID + col;
            else if (r < 33)   src = query + ((size_t)(b * QL + (r - 1))) * HID + col;
            else               src = doc   + ((size_t)(b * (D_ * SL) + (r - 33))) * HID + col;
#pragma unroll
            for (int j = 0; j < 16; j += 4) {
                float4 v = *reinterpret_cast<const float4*>(src + j);
                o[j] = f2bf(v.x); o[j+1] = f2bf(v.y);
                o[j+2] = f2bf(v.z); o[j+3] = f2bf(v.w);
            }
        } else {
#pragma unroll
            for (int j = 0; j < 16; ++j) o[j] = 0;
        }
        *reinterpret_cast<short8*>(X + idx)     = *reinterpret_cast<short8*>(&o[0]);
        *reinterpret_cast<short8*>(X + idx + 8) = *reinterpret_cast<short8*>(&o[8]);
    } else {
        int idx = ((bid - PACK_BLKS) * 256 + threadIdx.x) * 16;
        int z = idx / WSZ;
        int r = idx - z * WSZ;
        const float* src = (z == 0 ? Wq : (z == 1 ? Wk : Wv)) + r;
        float sc = (z == 0) ? QSF : 1.0f;   // fold qk-scale*log2e into Wq
        short o[16];
#pragma unroll
        for (int j = 0; j < 16; j += 4) {
            float4 v = *reinterpret_cast<const float4*>(src + j);
            o[j] = f2bf(v.x * sc); o[j+1] = f2bf(v.y * sc);
            o[j+2] = f2bf(v.z * sc); o[j+3] = f2bf(v.w * sc);
        }
        *reinterpret_cast<short8*>(Wb + idx)     = *reinterpret_cast<short8*>(&o[0]);
        *reinterpret_cast<short8*>(Wb + idx + 8) = *reinterpret_cast<short8*>(&o[8]);
    }
}

// ---------------------------------------------------------------------------
// Kernel 2: projection GEMM, 128x128 tile, BK=64 (12 K-steps), single-barrier
// double-buffered K-loop. Q/K/V in ONE dispatch. XOR chunk-swizzled LDS.
// Grid locality: fast dim = (n,z); XCD-chunked bijective remap (m204).
// zi==0 (Q): output pre-scaled by QSF (W and bias scaled).
// zi==2 (V): A=W-frag, B=X-frag so D[m=wcol][n=xrow]; Vt stores become
// 16-lane contiguous 32B runs along Vt's fast (token) dim.
// ---------------------------------------------------------------------------
__global__ __launch_bounds__(256) void proj4u(
    const short* __restrict__ X, const short* __restrict__ Wb,
    const float* __restrict__ bq, const float* __restrict__ bk,
    const float* __restrict__ bv,
    short* __restrict__ Qb, short* __restrict__ Kb, short* __restrict__ Vt)
{
    __shared__ short Xs[2][128 * 64];
    __shared__ short Ws[2][128 * 64];

    int tid = threadIdx.x, lane = tid & 63, wave = tid >> 6;

    // ---- XCD-aware bijective remap: nwg = 18*129 = 2322 = 8*290 + 2 ----
    int lin = blockIdx.x + 18 * blockIdx.y;
    {
        const int q = 290, r = 2;
        int xcd = lin & 7, seq = lin >> 3;
        lin = (xcd < r ? xcd * (q + 1) : r * (q + 1) + (xcd - r) * q) + seq;
    }
    int mblk = lin / 18;
    int nz   = lin - mblk * 18;
    int zi   = nz % 3;          // z fastest
    int nblk = nz / 3;
    bool vsw = (zi == 2);
    const short* W = Wb + (size_t)zi * WSZ;
    int m0 = mblk * 128, n0 = nblk * 128;

    int moff = (wave & 1) * 64, noff = (wave >> 1) * 64;
    int lr = lane & 15, lg = lane >> 4;

    // staging sources: slot s = p*256+tid -> row = s>>3, chunk c = s&7;
    // position c in LDS holds logical chunk (c ^ (row&7)) of the 64-K window.
    const short* xsrc[4];
    const short* wsrc[4];
#pragma unroll
    for (int p = 0; p < 4; ++p) {
        int s = p * 256 + tid;
        int row = s >> 3, c = s & 7;
        int col = (c ^ (row & 7)) * 8;
        xsrc[p] = X + (size_t)(m0 + row) * HID + col;
        wsrc[p] = W + (size_t)(n0 + row) * HID + col;
    }

    float4v acc[4][4];
    for (int mi = 0; mi < 4; ++mi)
        for (int ni = 0; ni < 4; ++ni)
            acc[mi][ni] = (float4v){0.f, 0.f, 0.f, 0.f};

#define PSTAGE(bufi, kt) do {                                               \
    _Pragma("unroll")                                                       \
    for (int p = 0; p < 4; ++p) {                                           \
        gl2lds16(xsrc[p] + (kt) * 64,                                       \
                 &Xs[bufi][(p * 256 + (tid & 0xC0)) * 8]);                  \
        gl2lds16(wsrc[p] + (kt) * 64,                                       \
                 &Ws[bufi][(p * 256 + (tid & 0xC0)) * 8]);                  \
    } } while (0)

    PSTAGE(0, 0);
#pragma unroll
    for (int kt = 0; kt < 12; ++kt) {
        __syncthreads();                     // drains stage(kt); prev compute done
        if (kt < 11) PSTAGE((kt + 1) & 1, kt + 1);
        const short* xb = Xs[kt & 1];
        const short* wb = Ws[kt & 1];
        short8 afl[4], afh[4], bfl[4], bfh[4];
        for (int mi = 0; mi < 4; ++mi) {
            int r = moff + mi * 16 + lr;
            int x0 = lg ^ (r & 7);
            afl[mi] = *reinterpret_cast<const short8*>(&xb[r * 64 + x0 * 8]);
            afh[mi] = *reinterpret_cast<const short8*>(&xb[r * 64 + (x0 ^ 4) * 8]);
        }
        for (int ni = 0; ni < 4; ++ni) {
            int r = noff + ni * 16 + lr;
            int x0 = lg ^ (r & 7);
            bfl[ni] = *reinterpret_cast<const short8*>(&wb[r * 64 + x0 * 8]);
            bfh[ni] = *reinterpret_cast<const short8*>(&wb[r * 64 + (x0 ^ 4) * 8]);
        }
        if (!vsw) {
            for (int mi = 0; mi < 4; ++mi)
                for (int ni = 0; ni < 4; ++ni) {
                    acc[mi][ni] = __builtin_amdgcn_mfma_f32_16x16x32_bf16(
                        afl[mi], bfl[ni], acc[mi][ni], 0, 0, 0);
                    acc[mi][ni] = __builtin_amdgcn_mfma_f32_16x16x32_bf16(
                        afh[mi], bfh[ni], acc[mi][ni], 0, 0, 0);
                }
        } else {
            for (int mi = 0; mi < 4; ++mi)
                for (int ni = 0; ni < 4; ++ni) {
                    acc[mi][ni] = __builtin_amdgcn_mfma_f32_16x16x32_bf16(
                        bfl[ni], afl[mi], acc[mi][ni], 0, 0, 0);
                    acc[mi][ni] = __builtin_amdgcn_mfma_f32_16x16x32_bf16(
                        bfh[ni], afh[mi], acc[mi][ni], 0, 0, 0);
                }
        }
    }
#undef PSTAGE

    if (!vsw) {
        short* Y = zi == 0 ? Qb : Kb;
        const float* bias = zi == 0 ? bq : bk;
        float bsc = zi == 0 ? QSF : 1.0f;
        for (int ni = 0; ni < 4; ++ni) {
            int gcol = n0 + noff + ni * 16 + lr;
            float bb = bias[gcol] * bsc;
            for (int mi = 0; mi < 4; ++mi) {
                int growb = m0 + moff + mi * 16 + lg * 4;
                for (int r = 0; r < 4; ++r)
                    Y[(size_t)(growb + r) * HID + gcol] = f2bf(acc[mi][ni][r] + bb);
            }
        }
    } else {
        // D[m=wcol = noff+ni*16+lg*4+r][n=xrow = moff+mi*16+lr]
        for (int ni = 0; ni < 4; ++ni) {
            float4 b4 = *reinterpret_cast<const float4*>(&bv[n0 + noff + ni * 16 + lg * 4]);
            const float* bbr = reinterpret_cast<const float*>(&b4);
            for (int mi = 0; mi < 4; ++mi) {
                int grow = m0 + moff + mi * 16 + lr;
                if (grow >= TOT_ROWS) continue;
                int b  = grow >= RPB ? 1 : 0;
                int rb = grow - b * RPB;
                int vr = rb < 33 ? rb : rb + 7;        // doc rows at 40+
                size_t cb = ((size_t)(b * HID + n0 + noff + ni * 16 + lg * 4)) * VT_R;
                for (int r = 0; r < 4; ++r)
                    Vt[cb + (size_t)r * VT_R + vr] = f2bf(acc[mi][ni][r] + bbr[r]);
            }
        }
    }
}

// ---------------------------------------------------------------------------
// Kernel 3: flash attention (S^T form), 128 q/block, 512 threads / 8 waves,
// 2-buffer ring (stage kt+1 issued at tile top, drained at tile-end barrier).
// ROUND-9: packed-f32 VALU diet — softmax on float4v so LLVM emits VOP3P
// v_pk_add/max_f32 (2 floats/inst): max tree 15->9, subtract 16->8, row sum
// 15->10; MFMA acc used directly as P (no copy); bare v_exp_f32 via
// __builtin_amdgcn_exp2f; kt-invariant fragment offsets hoisted.
// Softmax: Q pre-scaled; mask preloaded into QK^T acc; defer-max via
// per-lane max + __any; per-lane partial sums reduced in epilogue;
// in-register P->A-frag repack (cvt_pk + permlane).
// Token order: doc 0..511, cls 512, query 513..544, pad 545.. (-inf mask).
// ---------------------------------------------------------------------------
__global__ __launch_bounds__(512) void attn8(
    const short* __restrict__ Qb, const short* __restrict__ Kb,
    const short* __restrict__ Vt,
    const float* __restrict__ qmask, const float* __restrict__ dmask,
    float* __restrict__ out)
{
    __shared__ short Ks[2][64 * 64];
    __shared__ short Vs[2][64 * 64];
    __shared__ float maskv[576];

    int tid  = threadIdx.x;
    int lane = tid & 63, wave = tid >> 6;

    // ---- XCD-aware remap: nwg = 5*384 = 1920 = 8*240 ----
    int lin = blockIdx.x + 5 * blockIdx.y;
    {
        int xcd = lin & 7, seq = lin >> 3;
        lin = xcd * 240 + seq;
    }
    int hbd = lin / 5;
    int qc  = lin - hbd * 5;
    int h = hbd >> 5, bd = hbd & 31;
    int b = bd >> 4, d = bd & 15;

    int lr = lane & 15, lg = lane >> 4, lk = lg * 8;
    int base = b * RPB;
    const short* vbase = Vt + (size_t)(b * HID + h * HD) * VT_R;

    // ---- hoisted staging addresses: 512 threads cover the full 64x128B
    // tile (1 K slot + 1 V slot each); LDS base wave-uniform ----
    int loffK = (tid & 0x1C0) * 8;
    const short *kp, *vp, *kp8, *vp8;
    {
        int r = tid >> 3, c = tid & 7;
        int colsw = (c ^ (r & 7)) * 8;
        // tiles 0..7: token = kt*64 + r, all doc rows (linear in kt)
        kp  = Kb + (size_t)(base + 33 + d * SL + r) * HID + h * HD + colsw;
        vp  = vbase + (size_t)r * VT_R + 40 + d * SL + colsw;
        // tile 8: token 512+r -> row base+min(r,32); V: vr = chunk
        int r8 = r > 32 ? 32 : r;
        kp8 = Kb + (size_t)(base + r8) * HID + h * HD + colsw;
        vp8 = vbase + (size_t)r * VT_R + colsw;
    }

#define ALIN(bufi, kt) do {                                       \
    gl2lds16(kp + (size_t)(kt) * 64 * HID, &Ks[bufi][loffK]);     \
    gl2lds16(vp + (kt) * 64, &Vs[bufi][loffK]); } while (0)
#define A8(bufi) do {                                             \
    gl2lds16(kp8, &Ks[bufi][loffK]);                              \
    gl2lds16(vp8, &Vs[bufi][loffK]); } while (0)

    ALIN(0, 0);

    for (int i = tid; i < 576; i += 512) {   // strided (512 thr, 576 ent)
        float mv;
        if (i < 512)       mv = dmask[(size_t)(b * D_ + d) * SL + i];
        else if (i == 512) mv = 0.f;
        else if (i < 545)  mv = qmask[b * QL + (i - 513)];
        else               mv = -INFINITY;
        maskv[i] = mv * LOG2E;
    }

    short8 bq0, bq1;
    {
        int qtok = qc * 128 + wave * 16 + lr;
        int qrow = qtok < 512 ? base + 33 + d * SL + qtok : base + qtok - 512;
        const short* qp = Qb + (size_t)qrow * HID + h * HD + lk;
        bq0 = *reinterpret_cast<const short8*>(qp);
        bq1 = *reinterpret_cast<const short8*>(qp + 32);
    }

    // kt-invariant fragment offsets: r&7 == lr&7 (nt*16 is mult of 8)
    int fb0 = lr * 64 + ((lg ^ (lr & 7)) * 8);
    int fb1 = fb0 ^ 32;
    int mko = lg * 4;

    float m_i = -1e30f;
    float lp  = 0.f;                    // per-LANE partial row sum
    float4v o[4];
    for (int nt = 0; nt < 4; ++nt) o[nt] = (float4v){0.f, 0.f, 0.f, 0.f};

    __syncthreads();    // stage(0) landed, maskv visible

#pragma unroll
    for (int kt = 0; kt < 9; ++kt) {
        // stage(kt+1) first: max flight time before its drain at tile end
        if (kt < 7)       ALIN((kt + 1) & 1, kt + 1);
        else if (kt == 7) A8((kt + 1) & 1);

        const short* kb   = Ks[kt & 1];
        const short* vbuf = Vs[kt & 1];

        // ---- QK^T: lane holds P[key = kt*64+nt*16+lg*4+r][q = lr];
        //      mask pre-loaded into the accumulator, Q pre-scaled ----
        float4v p[4];
        short8 kf0[4], kf1[4];
#pragma unroll
        for (int nt = 0; nt < 4; ++nt) {
            kf0[nt] = *reinterpret_cast<const short8*>(&kb[nt * 1024 + fb0]);
            kf1[nt] = *reinterpret_cast<const short8*>(&kb[nt * 1024 + fb1]);
        }
        __builtin_amdgcn_s_setprio(1);
#pragma unroll
        for (int nt = 0; nt < 4; ++nt) {
            float4v z = *reinterpret_cast<const float4v*>(
                &maskv[kt * 64 + nt * 16 + mko]);
            z = __builtin_amdgcn_mfma_f32_16x16x32_bf16(kf0[nt], bq0, z, 0, 0, 0);
            z = __builtin_amdgcn_mfma_f32_16x16x32_bf16(kf1[nt], bq1, z, 0, 0, 0);
            p[nt] = z;
        }
        __builtin_amdgcn_s_setprio(0);

        // ---- per-LANE max, packed (v_pk_max_f32) ----
        float4v m01 = __builtin_elementwise_max(p[0], p[1]);
        float4v m23 = __builtin_elementwise_max(p[2], p[3]);
        float4v mm  = __builtin_elementwise_max(m01, m23);
        float lmax  = fmaxf(fmaxf(mm[0], mm[1]), fmaxf(mm[2], mm[3]));

        // ---- defer-max: rescale only if some row grows past m+8 ----
        if (__any(lmax > m_i + 8.0f)) {
            float tmx = fmaxf(lmax, __shfl_xor(lmax, 16));
            tmx = fmaxf(tmx, __shfl_xor(tmx, 32));       // row max (q=lr)
            float mnew = fmaxf(m_i, tmx);
            float alpha = exp2f(m_i - mnew);
            m_i = mnew;
            lp *= alpha;
            float al[4];
            for (int r = 0; r < 4; ++r) al[r] = __shfl(alpha, lg * 4 + r);
            for (int nt = 0; nt < 4; ++nt)
                for (int r = 0; r < 4; ++r) o[nt][r] *= al[r];
        }

        // ---- packed subtract + exp2 (P bounded by 2^8) ----
        float4v m4 = {m_i, m_i, m_i, m_i};
#pragma unroll
        for (int nt = 0; nt < 4; ++nt) {
            float4v t = p[nt] - m4;              // v_pk_add_f32 x2
            t[0] = __builtin_amdgcn_exp2f(t[0]);
            t[1] = __builtin_amdgcn_exp2f(t[1]);
            t[2] = __builtin_amdgcn_exp2f(t[2]);
            t[3] = __builtin_amdgcn_exp2f(t[3]);
            p[nt] = t;
        }
        // ---- packed row-sum partials ----
        float4v s01 = p[0] + p[1];
        float4v s23 = p[2] + p[3];
        float4v ss  = s01 + s23;                 // 6x v_pk_add_f32 total
        lp += (ss[0] + ss[1]) + (ss[2] + ss[3]);

        // ---- in-register P -> PV A-fragment repack ----
        unsigned int wa[4], wbv[4];
#pragma unroll
        for (int nt = 0; nt < 4; ++nt) {
            wa[nt]  = cvtpk(p[nt][0], p[nt][1]);
            wbv[nt] = cvtpk(p[nt][2], p[nt][3]);
        }
        uint2v tA01 = __builtin_amdgcn_permlane32_swap(wa[0],  wa[1],  false, false);
        uint2v uA01 = __builtin_amdgcn_permlane16_swap(tA01[0], tA01[1], false, false);
        uint2v tB01 = __builtin_amdgcn_permlane32_swap(wbv[0], wbv[1], false, false);
        uint2v uB01 = __builtin_amdgcn_permlane16_swap(tB01[0], tB01[1], false, false);
        uint2v tA23 = __builtin_amdgcn_permlane32_swap(wa[2],  wa[3],  false, false);
        uint2v uA23 = __builtin_amdgcn_permlane16_swap(tA23[0], tA23[1], false, false);
        uint2v tB23 = __builtin_amdgcn_permlane32_swap(wbv[2], wbv[3], false, false);
        uint2v uB23 = __builtin_amdgcn_permlane16_swap(tB23[0], tB23[1], false, false);

        union { unsigned int u[4]; short8 s8; } A0, A1;
        A0.u[0] = uA01[0]; A0.u[1] = uB01[0]; A0.u[2] = uA01[1]; A0.u[3] = uB01[1];
        A1.u[0] = uA23[0]; A1.u[1] = uB23[0]; A1.u[2] = uA23[1]; A1.u[3] = uB23[1];
        short8 ap0 = A0.s8;
        short8 ap1 = A1.s8;

        // ---- PV ----
        __builtin_amdgcn_s_setprio(1);
#pragma unroll
        for (int nt = 0; nt < 4; ++nt) {
            short8 bv0 = *reinterpret_cast<const short8*>(&vbuf[nt * 1024 + fb0]);
            short8 bv1 = *reinterpret_cast<const short8*>(&vbuf[nt * 1024 + fb1]);
            o[nt] = __builtin_amdgcn_mfma_f32_16x16x32_bf16(ap0, bv0, o[nt], 0, 0, 0);
            o[nt] = __builtin_amdgcn_mfma_f32_16x16x32_bf16(ap1, bv1, o[nt], 0, 0, 0);
        }
        __builtin_amdgcn_s_setprio(0);

        if (kt < 8) __syncthreads();   // drains stage(kt+1); buf[kt&1] reads done
    }
#undef ALIN
#undef A8

    {
        float lt = lp;
        lt += __shfl_xor(lt, 16);
        lt += __shfl_xor(lt, 32);           // row total (q=lr), replicated
        float li[4];
        for (int r = 0; r < 4; ++r) li[r] = __shfl(lt, lg * 4 + r);
        for (int r = 0; r < 4; ++r) {
            int t = qc * 128 + wave * 16 + lg * 4 + r;
            if (t >= SEQ) continue;
            int seq = t < 512 ? 33 + t : (t == 512 ? 0 : t - 512);
            float inv = 1.f / li[r];
            float* op = out + ((size_t)(bd * SEQ + seq)) * HID + h * HD + lr;
            for (int nt = 0; nt < 4; ++nt)
                op[nt * 16] = o[nt][r] * inv;
        }
    }
}

// ---------------------------------------------------------------------------
extern "C" void kernel_launch(void* const* d_in, const int* in_sizes, int n_in,
                              void* d_out, int out_size, void* d_ws, size_t ws_size,
                              hipStream_t stream)
{
    const float* cls   = (const float*)d_in[0];
    const float* query = (const float*)d_in[1];
    const float* doc   = (const float*)d_in[2];
    const float* qmask = (const float*)d_in[3];
    const float* dmask = (const float*)d_in[4];
    const float* Wq = (const float*)d_in[5];
    const float* bq = (const float*)d_in[6];
    const float* Wk = (const float*)d_in[7];
    const float* bk = (const float*)d_in[8];
    const float* Wv = (const float*)d_in[9];
    const float* bv = (const float*)d_in[10];
    float* out = (float*)d_out;

    short* X  = (short*)d_ws;
    size_t seg = (size_t)PAD_ROWS * HID;
    short* Qb = X + seg;
    short* Kb = Qb + seg;
    short* Vt = Kb + seg;                 // 2*768*8256 == seg
    short* Wb = (short*)d_out;            // scratch; attn8 overwrites all of out

    pack_all<<<dim3(PACK_BLKS + WPACK_BLKS), 256, 0, stream>>>(
        cls, query, doc, Wq, Wk, Wv, X, Wb);
    proj4u<<<dim3(18, 129, 1), 256, 0, stream>>>(X, Wb, bq, bk, bv, Qb, Kb, Vt);
    attn8<<<dim3(5, NH * 32, 1), 512, 0, stream>>>(Qb, Kb, Vt, qmask, dmask, out);
}